// Round 1
// baseline (756.586 us; speedup 1.0000x reference)
//
#include <hip/hip_runtime.h>
#include <math.h>

#define M_ROWS 78400
#define LSEQ   350
#define DDIM   768
#define NPAIR  224

typedef short bf16x8 __attribute__((ext_vector_type(8)));
typedef float f32x4  __attribute__((ext_vector_type(4)));

__device__ __forceinline__ unsigned short f2bf(float x) {
  unsigned int u = __float_as_uint(x);
  unsigned int r = (u + 0x7FFFu + ((u >> 16) & 1u)) >> 16;  // round-nearest-even
  return (unsigned short)r;
}

__device__ __forceinline__ float tanh_fast(float x) {
  float e = __expf(2.f * x);
  return 1.f - 2.f / (e + 1.f);
}

// ---------------- kernel 0: W1 -> W1t (transposed, bf16) ----------------
__global__ __launch_bounds__(256) void k_w1t(const float* __restrict__ W1,
                                             unsigned short* __restrict__ W1t) {
  __shared__ float tile[32][33];
  int bk = blockIdx.x * 32, bn = blockIdx.y * 32;
  int tx = threadIdx.x & 31, ty = threadIdx.x >> 5;
#pragma unroll
  for (int i = 0; i < 32; i += 8)
    tile[ty + i][tx] = W1[(size_t)(bk + ty + i) * DDIM + bn + tx];
  __syncthreads();
#pragma unroll
  for (int i = 0; i < 32; i += 8)
    W1t[(size_t)(bn + ty + i) * DDIM + bk + tx] = f2bf(tile[tx][ty + i]);
}

// ---------------- kernel 1: fused scores GEMM ----------------
// scores[row] += sum_n v1[n] * tanh( (X @ W1)[row][n] + b1[n] )  over this block's n-slab
__global__ __launch_bounds__(256, 2) void k_scores(
    const float* __restrict__ X, const unsigned short* __restrict__ W1t,
    const float* __restrict__ b1, const float* __restrict__ v1,
    float* __restrict__ scores) {
  __shared__ unsigned short As[128][40];  // stride 40 halves = 80B = 20 dwords -> 2-way only
  __shared__ unsigned short Bs[128][40];

  const int t = threadIdx.x;
  const int row0 = blockIdx.x * 128;
  const int n0 = blockIdx.y * 128;
  const int l15 = t & 15;
  const int quad = (t >> 4) & 3;
  const int w = t >> 6;
  const int wm = w >> 1, wn = w & 1;

  const int ar = t >> 3;         // A staging: row within pass
  const int ac = (t & 7) * 4;    // A staging: k offset (4 floats)
  const int br = t >> 2;         // B staging: row within pass
  const int bc = (t & 3) * 8;    // B staging: k offset (8 bf16)

  f32x4 acc[4][4];
#pragma unroll
  for (int mi = 0; mi < 4; ++mi)
#pragma unroll
    for (int ni = 0; ni < 4; ++ni)
#pragma unroll
      for (int r = 0; r < 4; ++r) acc[mi][ni][r] = 0.f;

  for (int k0 = 0; k0 < DDIM; k0 += 32) {
    // stage A: 128 rows x 32 k, fp32 -> bf16
#pragma unroll
    for (int pass = 0; pass < 4; ++pass) {
      int r = ar + pass * 32;
      int row = row0 + r;
      float4 x = make_float4(0.f, 0.f, 0.f, 0.f);
      if (row < M_ROWS) x = *(const float4*)(X + (size_t)row * DDIM + k0 + ac);
      unsigned int lo = (unsigned int)f2bf(x.x) | ((unsigned int)f2bf(x.y) << 16);
      unsigned int hi = (unsigned int)f2bf(x.z) | ((unsigned int)f2bf(x.w) << 16);
      *(uint2*)&As[r][ac] = make_uint2(lo, hi);
    }
    // stage B: 128 n-rows x 32 k (already bf16, already [n][k])
#pragma unroll
    for (int pp = 0; pp < 2; ++pp) {
      int r = br + pp * 64;
      uint4 v = *(const uint4*)(W1t + (size_t)(n0 + r) * DDIM + k0 + bc);
      *(uint4*)&Bs[r][bc] = v;
    }
    __syncthreads();

    bf16x8 a[4], b[4];
#pragma unroll
    for (int mi = 0; mi < 4; ++mi)
      a[mi] = *(const bf16x8*)&As[wm * 64 + mi * 16 + l15][quad * 8];
#pragma unroll
    for (int ni = 0; ni < 4; ++ni)
      b[ni] = *(const bf16x8*)&Bs[wn * 64 + ni * 16 + l15][quad * 8];
#pragma unroll
    for (int mi = 0; mi < 4; ++mi)
#pragma unroll
      for (int ni = 0; ni < 4; ++ni)
        acc[mi][ni] = __builtin_amdgcn_mfma_f32_16x16x32_bf16(a[mi], b[ni], acc[mi][ni], 0, 0, 0);
    __syncthreads();
  }

  // epilogue: tanh + dot v1 over this block's 128 n-cols, reduce, atomic
  float v1v[4], b1v[4];
#pragma unroll
  for (int ni = 0; ni < 4; ++ni) {
    int n = n0 + wn * 64 + ni * 16 + l15;
    v1v[ni] = v1[n];
    b1v[ni] = b1[n];
  }
#pragma unroll
  for (int mi = 0; mi < 4; ++mi) {
#pragma unroll
    for (int reg = 0; reg < 4; ++reg) {
      float s = 0.f;
#pragma unroll
      for (int ni = 0; ni < 4; ++ni)
        s += tanh_fast(acc[mi][ni][reg] + b1v[ni]) * v1v[ni];
      s += __shfl_xor(s, 1);
      s += __shfl_xor(s, 2);
      s += __shfl_xor(s, 4);
      s += __shfl_xor(s, 8);
      if (l15 == mi * 4 + reg) {
        int row = row0 + wm * 64 + mi * 16 + quad * 4 + reg;
        if (row < M_ROWS) atomicAdd(&scores[row], s);
      }
    }
  }
}

// ---------------- kernel 2: masked two-range softmax pooling + pair_embeddings copy ----------------
__global__ __launch_bounds__(256) void k_pool(
    const float* __restrict__ X, const float* __restrict__ scores,
    const int* __restrict__ fsep, const int* __restrict__ ssep,
    float* __restrict__ emb, float* __restrict__ out) {
  const int p = blockIdx.x;
  const int t = threadIdx.x;
  const int fs = fsep[p], ss = ssep[p];
  __shared__ float sw1[LSEQ], sw2[LSEQ];
  __shared__ float red[256];

  for (int l = t; l < LSEQ; l += 256) {
    float s = scores[p * LSEQ + l];
    sw1[l] = (l >= 1 && l < fs) ? s : -INFINITY;
    sw2[l] = (l > fs && l < ss) ? s : -INFINITY;
  }
  __syncthreads();

  // max of range 1
  float m = -INFINITY;
  for (int l = t; l < LSEQ; l += 256) m = fmaxf(m, sw1[l]);
  red[t] = m;
  __syncthreads();
  for (int s = 128; s > 0; s >>= 1) {
    if (t < s) red[t] = fmaxf(red[t], red[t + s]);
    __syncthreads();
  }
  float m1 = red[0];
  __syncthreads();
  // max of range 2
  m = -INFINITY;
  for (int l = t; l < LSEQ; l += 256) m = fmaxf(m, sw2[l]);
  red[t] = m;
  __syncthreads();
  for (int s = 128; s > 0; s >>= 1) {
    if (t < s) red[t] = fmaxf(red[t], red[t + s]);
    __syncthreads();
  }
  float m2 = red[0];
  __syncthreads();

  // exp + denom 1
  float sum = 0.f;
  for (int l = t; l < LSEQ; l += 256) {
    float e = __expf(sw1[l] - m1);
    sw1[l] = e;
    sum += e;
  }
  red[t] = sum;
  __syncthreads();
  for (int s = 128; s > 0; s >>= 1) {
    if (t < s) red[t] += red[t + s];
    __syncthreads();
  }
  float inv1 = 1.f / red[0];
  __syncthreads();
  // exp + denom 2
  sum = 0.f;
  for (int l = t; l < LSEQ; l += 256) {
    float e = __expf(sw2[l] - m2);
    sw2[l] = e;
    sum += e;
  }
  red[t] = sum;
  __syncthreads();
  for (int s = 128; s > 0; s >>= 1) {
    if (t < s) red[t] += red[t + s];
    __syncthreads();
  }
  float inv2 = 1.f / red[0];
  __syncthreads();

  for (int l = t; l < LSEQ; l += 256) {
    sw1[l] *= inv1;
    sw2[l] *= inv2;
  }
  __syncthreads();

  const float* base = X + (size_t)p * LSEQ * DDIM;
  float a10 = 0.f, a11 = 0.f, a12 = 0.f, a20 = 0.f, a21 = 0.f, a22 = 0.f;
  for (int l = 1; l < ss; ++l) {
    float wa = sw1[l], wb = sw2[l];
    const float* rowp = base + (size_t)l * DDIM + t;
    float x0 = rowp[0], x1 = rowp[256], x2 = rowp[512];
    a10 += wa * x0; a11 += wa * x1; a12 += wa * x2;
    a20 += wb * x0; a21 += wb * x1; a22 += wb * x2;
  }
  float* e1 = emb + (size_t)(2 * p) * DDIM;
  float* e2 = emb + (size_t)(2 * p + 1) * DDIM;
  e1[t] = a10; e1[t + 256] = a11; e1[t + 512] = a12;
  e2[t] = a20; e2[t + 256] = a21; e2[t + 512] = a22;
  // pair_embeddings = all_output[:, 0, :]
  float* po = out + (size_t)p * DDIM;
  po[t] = base[t]; po[t + 256] = base[t + 256]; po[t + 512] = base[t + 512];
}

// ---------------- kernel 3: sc = tanh(emb @ W2 + b2) @ v2 ----------------
__global__ __launch_bounds__(256) void k_mlp2(
    const float* __restrict__ emb, const float* __restrict__ W2,
    const float* __restrict__ b2, const float* __restrict__ v2,
    float* __restrict__ sc) {
  const int r0 = blockIdx.x * 4;
  const int t = threadIdx.x;
  __shared__ float rows[4][DDIM];
  __shared__ float4 red[256];
  for (int i = t; i < 4 * DDIM; i += 256)
    rows[i / DDIM][i % DDIM] = emb[(size_t)r0 * DDIM + i];
  __syncthreads();

  float acc[4][3];
  float b2v0 = b2[t], b2v1 = b2[t + 256], b2v2 = b2[t + 512];
#pragma unroll
  for (int r = 0; r < 4; ++r) {
    acc[r][0] = b2v0; acc[r][1] = b2v1; acc[r][2] = b2v2;
  }
  for (int k = 0; k < DDIM; ++k) {
    float w0 = W2[(size_t)k * DDIM + t];
    float w1 = W2[(size_t)k * DDIM + t + 256];
    float w2 = W2[(size_t)k * DDIM + t + 512];
#pragma unroll
    for (int r = 0; r < 4; ++r) {
      float xv = rows[r][k];
      acc[r][0] += xv * w0; acc[r][1] += xv * w1; acc[r][2] += xv * w2;
    }
  }
  float v2v0 = v2[t], v2v1 = v2[t + 256], v2v2 = v2[t + 512];
  float4 lr;
  lr.x = tanh_fast(acc[0][0]) * v2v0 + tanh_fast(acc[0][1]) * v2v1 + tanh_fast(acc[0][2]) * v2v2;
  lr.y = tanh_fast(acc[1][0]) * v2v0 + tanh_fast(acc[1][1]) * v2v1 + tanh_fast(acc[1][2]) * v2v2;
  lr.z = tanh_fast(acc[2][0]) * v2v0 + tanh_fast(acc[2][1]) * v2v1 + tanh_fast(acc[2][2]) * v2v2;
  lr.w = tanh_fast(acc[3][0]) * v2v0 + tanh_fast(acc[3][1]) * v2v1 + tanh_fast(acc[3][2]) * v2v2;
  red[t] = lr;
  __syncthreads();
  for (int s = 128; s > 0; s >>= 1) {
    if (t < s) {
      red[t].x += red[t + s].x; red[t].y += red[t + s].y;
      red[t].z += red[t + s].z; red[t].w += red[t + s].w;
    }
    __syncthreads();
  }
  if (t == 0) {
    sc[r0 + 0] = red[0].x; sc[r0 + 1] = red[0].y;
    sc[r0 + 2] = red[0].z; sc[r0 + 3] = red[0].w;
  }
}

// ---------------- kernel 4: segment softmax + weighted sum ----------------
__device__ __forceinline__ int seg_of(int e) {
  int p = e >> 1;
  int z = p / 56;
  int r = p - z * 56;
  int j = r / 7;
  int kk = r - j * 7;
  int k = kk + (kk >= j ? 1 : 0);
  return z * 8 + ((e & 1) ? k : j);
}

__global__ __launch_bounds__(256) void k_segout(
    const float* __restrict__ emb, const float* __restrict__ sc,
    float* __restrict__ out2) {
  const int g = blockIdx.x;
  const int t = threadIdx.x;
  float m = -INFINITY;
  for (int e = 0; e < 2 * NPAIR; ++e)
    if (seg_of(e) == g) m = fmaxf(m, sc[e]);
  float den = 0.f;
  for (int e = 0; e < 2 * NPAIR; ++e)
    if (seg_of(e) == g) den += __expf(sc[e] - m);
  float inv = 1.f / den;
  float a0 = 0.f, a1 = 0.f, a2 = 0.f;
  for (int e = 0; e < 2 * NPAIR; ++e) {
    if (seg_of(e) != g) continue;
    float w = __expf(sc[e] - m) * inv;
    const float* er = emb + (size_t)e * DDIM;
    a0 += w * er[t]; a1 += w * er[t + 256]; a2 += w * er[t + 512];
  }
  out2[(size_t)g * DDIM + t] = a0;
  out2[(size_t)g * DDIM + t + 256] = a1;
  out2[(size_t)g * DDIM + t + 512] = a2;
}

// ---------------- launcher ----------------
extern "C" void kernel_launch(void* const* d_in, const int* in_sizes, int n_in,
                              void* d_out, int out_size, void* d_ws, size_t ws_size,
                              hipStream_t stream) {
  const float* X  = (const float*)d_in[0];
  const int* fs   = (const int*)d_in[1];
  const int* ss   = (const int*)d_in[2];
  const float* W1 = (const float*)d_in[3];
  const float* b1 = (const float*)d_in[4];
  const float* v1 = (const float*)d_in[5];
  // d_in[6] = vb1 (shift-invariant under softmax -> unused)
  const float* W2 = (const float*)d_in[7];
  const float* b2 = (const float*)d_in[8];
  const float* v2 = (const float*)d_in[9];
  // d_in[10] = vb2 (unused)
  float* out = (float*)d_out;

  char* ws = (char*)d_ws;
  unsigned short* W1t = (unsigned short*)ws;       // 768*768*2       = 1,179,648 B
  float* scores = (float*)(ws + 1179648);          // 78400*4         =   313,600 B
  float* emb    = (float*)(ws + 1493248);          // 448*768*4       = 1,376,256 B
  float* sc     = (float*)(ws + 2869504);          // 448*4           =     1,792 B

  k_w1t<<<dim3(24, 24), 256, 0, stream>>>(W1, W1t);
  hipMemsetAsync(scores, 0, 78400 * sizeof(float), stream);
  k_scores<<<dim3(613, 6), 256, 0, stream>>>(X, W1t, b1, v1, scores);
  k_pool<<<NPAIR, 256, 0, stream>>>(X, scores, fs, ss, emb, out);
  k_mlp2<<<112, 256, 0, stream>>>(emb, W2, b2, v2, sc);
  k_segout<<<32, 256, 0, stream>>>(emb, sc, out + NPAIR * DDIM);
}

// Round 2
// 684.248 us; speedup vs baseline: 1.1057x; 1.1057x over previous
//
#include <hip/hip_runtime.h>
#include <math.h>

#define LSEQ   350
#define DDIM   768
#define NPAIR  224
#define MROWS1 78400

typedef short bf16x8 __attribute__((ext_vector_type(8)));
typedef float f32x4  __attribute__((ext_vector_type(4)));

__device__ __forceinline__ unsigned short f2bf(float x) {
  unsigned int u = __float_as_uint(x);
  unsigned int r = (u + 0x7FFFu + ((u >> 16) & 1u)) >> 16;  // RNE
  return (unsigned short)r;
}

__device__ __forceinline__ float tanh_fast(float x) {
  float e = __expf(2.f * x);
  return 1.f - 2.f / (e + 1.f);
}

// ---------------- kernel 0: W -> Wt (transposed, bf16) ----------------
__global__ __launch_bounds__(256) void k_w1t(const float* __restrict__ W,
                                             unsigned short* __restrict__ Wt) {
  __shared__ float tile[32][33];
  int bk = blockIdx.x * 32, bn = blockIdx.y * 32;
  int tx = threadIdx.x & 31, ty = threadIdx.x >> 5;
#pragma unroll
  for (int i = 0; i < 32; i += 8)
    tile[ty + i][tx] = W[(size_t)(bk + ty + i) * DDIM + bn + tx];
  __syncthreads();
#pragma unroll
  for (int i = 0; i < 32; i += 8)
    Wt[(size_t)(bn + ty + i) * DDIM + bk + tx] = f2bf(tile[tx][ty + i]);
}

// ---------------- kernel 1: fused scores GEMM (runtime M) ----------------
// outs[row] += sum_n vv[n] * tanh( (X @ W)[row][n] + bias[n] ) over this block's n-slab
// grid = (DDIM/128, ceil(M/128)) -- n is blockIdx.x (fastest) so the 6 n-blocks
// sharing a row-slab are dispatch-adjacent -> A re-reads hit L2/L3, HBM reads X once.
__global__ __launch_bounds__(256, 2) void k_gemm_score(
    const float* __restrict__ X, const unsigned short* __restrict__ Wt,
    const float* __restrict__ bias, const float* __restrict__ vv,
    float* __restrict__ outs, int Mrows) {
  __shared__ unsigned short As[128][40];  // stride 40 halves = 80B -> only 2-way bank alias (free)
  __shared__ unsigned short Bs[128][40];

  const int t = threadIdx.x;
  const int n0 = blockIdx.x * 128;
  const int row0 = blockIdx.y * 128;
  const int l15 = t & 15;
  const int quad = (t >> 4) & 3;
  const int w = t >> 6;
  const int wm = w >> 1, wn = w & 1;

  const int ar = t >> 3;       // A staging: row within pass
  const int ac = (t & 7) * 4;  // A staging: k offset (4 floats)
  const int br = t >> 2;       // B staging: row within pass
  const int bc = (t & 3) * 8;  // B staging: k offset (8 bf16)

  f32x4 acc[4][4];
#pragma unroll
  for (int mi = 0; mi < 4; ++mi)
#pragma unroll
    for (int ni = 0; ni < 4; ++ni)
#pragma unroll
      for (int r = 0; r < 4; ++r) acc[mi][ni][r] = 0.f;

  for (int k0 = 0; k0 < DDIM; k0 += 32) {
    // stage A: 128 rows x 32 k, fp32 -> bf16 (round-half-up + v_perm pack)
#pragma unroll
    for (int pass = 0; pass < 4; ++pass) {
      int r = ar + pass * 32;
      int row = row0 + r;
      float4 x = make_float4(0.f, 0.f, 0.f, 0.f);
      if (row < Mrows) x = *(const float4*)(X + (size_t)row * DDIM + k0 + ac);
      unsigned int ux = __float_as_uint(x.x) + 0x8000u;
      unsigned int uy = __float_as_uint(x.y) + 0x8000u;
      unsigned int uz = __float_as_uint(x.z) + 0x8000u;
      unsigned int uw = __float_as_uint(x.w) + 0x8000u;
      unsigned int lo = __builtin_amdgcn_perm(uy, ux, 0x07060302u);  // {y.hi16, x.hi16}
      unsigned int hi = __builtin_amdgcn_perm(uw, uz, 0x07060302u);
      *(uint2*)&As[r][ac] = make_uint2(lo, hi);
    }
    // stage B: 128 n-rows x 32 k (bf16, [n][k])
#pragma unroll
    for (int pp = 0; pp < 2; ++pp) {
      int r = br + pp * 64;
      uint4 v = *(const uint4*)(Wt + (size_t)(n0 + r) * DDIM + k0 + bc);
      *(uint4*)&Bs[r][bc] = v;
    }
    __syncthreads();

    bf16x8 a[4], b[4];
#pragma unroll
    for (int mi = 0; mi < 4; ++mi)
      a[mi] = *(const bf16x8*)&As[wm * 64 + mi * 16 + l15][quad * 8];
#pragma unroll
    for (int ni = 0; ni < 4; ++ni)
      b[ni] = *(const bf16x8*)&Bs[wn * 64 + ni * 16 + l15][quad * 8];
#pragma unroll
    for (int mi = 0; mi < 4; ++mi)
#pragma unroll
      for (int ni = 0; ni < 4; ++ni)
        acc[mi][ni] = __builtin_amdgcn_mfma_f32_16x16x32_bf16(a[mi], b[ni], acc[mi][ni], 0, 0, 0);
    __syncthreads();
  }

  // epilogue: tanh + dot vv over this block's 128 n-cols, shuffle-reduce, atomic
  float vvv[4], bbv[4];
#pragma unroll
  for (int ni = 0; ni < 4; ++ni) {
    int n = n0 + wn * 64 + ni * 16 + l15;
    vvv[ni] = vv[n];
    bbv[ni] = bias[n];
  }
#pragma unroll
  for (int mi = 0; mi < 4; ++mi) {
#pragma unroll
    for (int reg = 0; reg < 4; ++reg) {
      float s = 0.f;
#pragma unroll
      for (int ni = 0; ni < 4; ++ni)
        s += tanh_fast(acc[mi][ni][reg] + bbv[ni]) * vvv[ni];
      s += __shfl_xor(s, 1);
      s += __shfl_xor(s, 2);
      s += __shfl_xor(s, 4);
      s += __shfl_xor(s, 8);
      if (l15 == mi * 4 + reg) {
        int row = row0 + wm * 64 + mi * 16 + quad * 4 + reg;
        if (row < Mrows) atomicAdd(&outs[row], s);
      }
    }
  }
}

// ---------------- block reduce helper ----------------
__device__ __forceinline__ float block_reduce(float v, bool is_max, float* redbuf) {
#pragma unroll
  for (int off = 1; off < 64; off <<= 1) {
    float o = __shfl_xor(v, off);
    v = is_max ? fmaxf(v, o) : (v + o);
  }
  int wv = threadIdx.x >> 6;
  if ((threadIdx.x & 63) == 0) redbuf[wv] = v;
  __syncthreads();
  float r = is_max ? fmaxf(fmaxf(redbuf[0], redbuf[1]), fmaxf(redbuf[2], redbuf[3]))
                   : (redbuf[0] + redbuf[1] + redbuf[2] + redbuf[3]);
  __syncthreads();
  return r;
}

// ---------------- kernel 2: masked two-range softmax pooling ----------------
// grid (NPAIR, 4): blockIdx.y = l-chunk; partial weighted sums atomicAdd'ed into
// zero-initialized emb. Softmax weights recomputed redundantly per chunk (cheap).
__global__ __launch_bounds__(256) void k_pool(
    const float* __restrict__ X, const float* __restrict__ scores,
    const int* __restrict__ fsep, const int* __restrict__ ssep,
    float* __restrict__ emb, float* __restrict__ out) {
  const int p = blockIdx.x;
  const int c = blockIdx.y;
  const int t = threadIdx.x;
  const int fs = fsep[p], ss = ssep[p];
  __shared__ float sw1[LSEQ], sw2[LSEQ];
  __shared__ float redbuf[4];

  float m1p = -INFINITY, m2p = -INFINITY;
  for (int l = t; l < LSEQ; l += 256) {
    float s = scores[p * LSEQ + l];
    float s1 = (l >= 1 && l < fs) ? s : -INFINITY;
    float s2 = (l > fs && l < ss) ? s : -INFINITY;
    sw1[l] = s1;
    sw2[l] = s2;
    m1p = fmaxf(m1p, s1);
    m2p = fmaxf(m2p, s2);
  }
  __syncthreads();
  float m1 = block_reduce(m1p, true, redbuf);
  float m2 = block_reduce(m2p, true, redbuf);

  float d1p = 0.f, d2p = 0.f;
  for (int l = t; l < LSEQ; l += 256) {
    float e1v = __expf(sw1[l] - m1);
    float e2v = __expf(sw2[l] - m2);
    sw1[l] = e1v;
    sw2[l] = e2v;
    d1p += e1v;
    d2p += e2v;
  }
  __syncthreads();
  float inv1 = 1.f / block_reduce(d1p, false, redbuf);
  float inv2 = 1.f / block_reduce(d2p, false, redbuf);

  const float* base = X + (size_t)p * LSEQ * DDIM;
  float a10 = 0.f, a11 = 0.f, a12 = 0.f, a20 = 0.f, a21 = 0.f, a22 = 0.f;
  for (int l = 1 + c; l < ss; l += 4) {
    float wa = sw1[l] * inv1, wb = sw2[l] * inv2;
    const float* rowp = base + (size_t)l * DDIM + t;
    float x0 = rowp[0], x1 = rowp[256], x2 = rowp[512];
    a10 += wa * x0; a11 += wa * x1; a12 += wa * x2;
    a20 += wb * x0; a21 += wb * x1; a22 += wb * x2;
  }
  float* e1 = emb + (size_t)(2 * p) * DDIM;
  float* e2 = emb + (size_t)(2 * p + 1) * DDIM;
  atomicAdd(&e1[t], a10); atomicAdd(&e1[t + 256], a11); atomicAdd(&e1[t + 512], a12);
  atomicAdd(&e2[t], a20); atomicAdd(&e2[t + 256], a21); atomicAdd(&e2[t + 512], a22);

  if (c == 0) {  // pair_embeddings = all_output[:, 0, :] (exact copy)
    float* po = out + (size_t)p * DDIM;
    po[t] = base[t]; po[t + 256] = base[t + 256]; po[t + 512] = base[t + 512];
  }
}

// ---------------- kernel 3: segment softmax + weighted sum (direct enumeration) ----------------
__global__ __launch_bounds__(256) void k_segout(
    const float* __restrict__ emb, const float* __restrict__ sc,
    float* __restrict__ out2) {
  const int g = blockIdx.x;  // 0..31
  const int z = g >> 3, j = g & 7;
  const int t = threadIdx.x;
  int ee[14];
#pragma unroll
  for (int i = 0; i < 7; ++i) ee[i] = 2 * (z * 56 + j * 7 + i);  // slot-0 entries
#pragma unroll
  for (int i = 0; i < 7; ++i) {  // slot-1 entries: pairs (j2, j), j2 != j
    int j2 = i + (i >= j ? 1 : 0);
    int kk = j - (j > j2 ? 1 : 0);
    ee[7 + i] = 2 * (z * 56 + j2 * 7 + kk) + 1;
  }
  float sv[14];
  float m = -INFINITY;
#pragma unroll
  for (int i = 0; i < 14; ++i) { sv[i] = sc[ee[i]]; m = fmaxf(m, sv[i]); }
  float den = 0.f;
#pragma unroll
  for (int i = 0; i < 14; ++i) { sv[i] = __expf(sv[i] - m); den += sv[i]; }
  float inv = 1.f / den;
  float a0 = 0.f, a1 = 0.f, a2 = 0.f;
#pragma unroll
  for (int i = 0; i < 14; ++i) {
    float wgt = sv[i] * inv;
    const float* er = emb + (size_t)ee[i] * DDIM;
    a0 += wgt * er[t]; a1 += wgt * er[t + 256]; a2 += wgt * er[t + 512];
  }
  out2[(size_t)g * DDIM + t] = a0;
  out2[(size_t)g * DDIM + t + 256] = a1;
  out2[(size_t)g * DDIM + t + 512] = a2;
}

// ---------------- launcher ----------------
extern "C" void kernel_launch(void* const* d_in, const int* in_sizes, int n_in,
                              void* d_out, int out_size, void* d_ws, size_t ws_size,
                              hipStream_t stream) {
  const float* X  = (const float*)d_in[0];
  const int* fs   = (const int*)d_in[1];
  const int* ss   = (const int*)d_in[2];
  const float* W1 = (const float*)d_in[3];
  const float* b1 = (const float*)d_in[4];
  const float* v1 = (const float*)d_in[5];
  // d_in[6] = vb1: shift-invariant under softmax -> unused
  const float* W2 = (const float*)d_in[7];
  const float* b2 = (const float*)d_in[8];
  const float* v2 = (const float*)d_in[9];
  // d_in[10] = vb2: unused
  float* out = (float*)d_out;

  char* ws = (char*)d_ws;
  unsigned short* Wt = (unsigned short*)ws;         // 768*768*2 = 1,179,648 B (W1t, then W2t)
  float* scores = (float*)(ws + 1179648);           // 78400*4 = 313,600 B (reused as sc: 448*4)
  float* emb    = (float*)(ws + 1493248);           // 448*768*4 = 1,376,256 B
  float* sc     = scores;                           // alias: scores dead after k_pool

  // Stage A: scores = tanh(X@W1+b1)@v1
  k_w1t<<<dim3(24, 24), 256, 0, stream>>>(W1, Wt);
  hipMemsetAsync(scores, 0, 78400 * sizeof(float), stream);
  hipMemsetAsync(emb, 0, 448 * DDIM * sizeof(float), stream);
  k_gemm_score<<<dim3(6, 613), 256, 0, stream>>>(X, Wt, b1, v1, scores, MROWS1);
  // Stage B: masked two-range softmax pooling (+ pair_embeddings copy)
  k_pool<<<dim3(NPAIR, 4), 256, 0, stream>>>(X, scores, fs, ss, emb, out);
  // Stage C: sc = tanh(emb@W2+b2)@v2 via the same MFMA kernel
  k_w1t<<<dim3(24, 24), 256, 0, stream>>>(W2, Wt);
  hipMemsetAsync(sc, 0, 448 * sizeof(float), stream);
  k_gemm_score<<<dim3(6, 4), 256, 0, stream>>>(emb, Wt, b2, v2, sc, 448);
  // Stage D: segment softmax + weighted sum
  k_segout<<<32, 256, 0, stream>>>(emb, sc, out + (size_t)NPAIR * DDIM);
}